// Round 2
// baseline (779.885 us; speedup 1.0000x reference)
//
#include <hip/hip_runtime.h>

typedef unsigned short u16;
typedef unsigned int   u32;

typedef __bf16 bf16x8 __attribute__((ext_vector_type(8)));
typedef float  f32x4  __attribute__((ext_vector_type(4)));

__device__ __forceinline__ float bf2f(u16 u){ u32 x = ((u32)u) << 16; return __builtin_bit_cast(float, x); }
__device__ __forceinline__ u16 f2bf(float f){
  u32 u = __builtin_bit_cast(u32, f);
  u32 r = (u + 0x7FFFu + ((u >> 16) & 1u)) >> 16;
  return (u16)r;
}

// ---------------- transpose + f32->bf16 cast: dst[c][r] = bf16(src[r][c]) ----------------
__global__ __launch_bounds__(256) void transpose_f32_bf16(const float* __restrict__ src,
                                                          u16* __restrict__ dst, int R, int C){
  __shared__ u16 tile[32][33];
  int c0 = blockIdx.x * 32, r0 = blockIdx.y * 32;
  int tx = threadIdx.x & 31, ty = threadIdx.x >> 5;   // ty: 0..7
  #pragma unroll
  for (int i = ty; i < 32; i += 8) tile[i][tx] = f2bf(src[(size_t)(r0 + i) * C + (c0 + tx)]);
  __syncthreads();
  #pragma unroll
  for (int i = ty; i < 32; i += 8) dst[(size_t)(c0 + i) * R + (r0 + tx)] = tile[tx][i];
}

// ---------------- C = A * BT^T  (A: [M][K] f32 or bf16, BT: [N][K] bf16) ----------------
// MFMA 16x16x32 bf16. Verified fragment maps (learn_hip m89/m91):
//   A frag: lane holds A[m=lane&15][k=quad*8+j]; B frag from BT rows same addressing.
//   C/D:    col=lane&15, row=quad*4+reg.
template<int BM, int BN, bool A_F32, bool OUT_BF16>
__global__ __launch_bounds__(256) void gemm_bt(const void* __restrict__ Aptr,
                                               const u16* __restrict__ BT,
                                               void* __restrict__ Cout,
                                               int M, int N, int K){
  constexpr int BK  = 32;
  constexpr int LDT = BK + 8;            // 40 elems = 80 B stride: 16B-aligned rows, 2-way banks (free)
  __shared__ u16 As[BM * LDT];
  __shared__ u16 Bs[BN * LDT];
  const int tid  = threadIdx.x;
  const int wave = tid >> 6, lane = tid & 63;
  const int row  = lane & 15, quad = lane >> 4;
  constexpr int WM = BM / 2, WN = BN / 2;
  const int wm = (wave >> 1) * WM, wn = (wave & 1) * WN;
  constexpr int MT = WM / 16, NT = WN / 16;
  const int m0 = blockIdx.y * BM, n0 = blockIdx.x * BN;

  const f32x4 zero = {0.f, 0.f, 0.f, 0.f};
  f32x4 acc[MT][NT];
  #pragma unroll
  for (int mt = 0; mt < MT; ++mt)
    #pragma unroll
    for (int nt = 0; nt < NT; ++nt) acc[mt][nt] = zero;

  constexpr int ACH = BM * BK / 8 / 256;  // 8-elem chunks per thread (A)
  constexpr int BCH = BN * BK / 8 / 256;

  for (int k0 = 0; k0 < K; k0 += BK) {
    #pragma unroll
    for (int c = 0; c < ACH; ++c) {
      int idx = tid + c * 256;
      int r = idx >> 2, kk = (idx & 3) * 8;
      if (A_F32) {
        const float* ap = (const float*)Aptr + (size_t)(m0 + r) * K + k0 + kk;
        float4 f0 = *(const float4*)ap;
        float4 f1 = *(const float4*)(ap + 4);
        u16 tmp[8];
        tmp[0] = f2bf(f0.x); tmp[1] = f2bf(f0.y); tmp[2] = f2bf(f0.z); tmp[3] = f2bf(f0.w);
        tmp[4] = f2bf(f1.x); tmp[5] = f2bf(f1.y); tmp[6] = f2bf(f1.z); tmp[7] = f2bf(f1.w);
        *(uint4*)&As[r * LDT + kk] = *(const uint4*)tmp;
      } else {
        *(uint4*)&As[r * LDT + kk] = *(const uint4*)((const u16*)Aptr + (size_t)(m0 + r) * K + k0 + kk);
      }
    }
    #pragma unroll
    for (int c = 0; c < BCH; ++c) {
      int idx = tid + c * 256;
      int r = idx >> 2, kk = (idx & 3) * 8;
      *(uint4*)&Bs[r * LDT + kk] = *(const uint4*)(BT + (size_t)(n0 + r) * K + k0 + kk);
    }
    __syncthreads();
    bf16x8 af[MT], bfr[NT];
    #pragma unroll
    for (int mt = 0; mt < MT; ++mt) af[mt]  = *(const bf16x8*)&As[(wm + mt * 16 + row) * LDT + quad * 8];
    #pragma unroll
    for (int nt = 0; nt < NT; ++nt) bfr[nt] = *(const bf16x8*)&Bs[(wn + nt * 16 + row) * LDT + quad * 8];
    #pragma unroll
    for (int mt = 0; mt < MT; ++mt)
      #pragma unroll
      for (int nt = 0; nt < NT; ++nt)
        acc[mt][nt] = __builtin_amdgcn_mfma_f32_16x16x32_bf16(af[mt], bfr[nt], acc[mt][nt], 0, 0, 0);
    __syncthreads();
  }

  #pragma unroll
  for (int mt = 0; mt < MT; ++mt)
    #pragma unroll
    for (int nt = 0; nt < NT; ++nt)
      #pragma unroll
      for (int r = 0; r < 4; ++r) {
        int rr = m0 + wm + mt * 16 + quad * 4 + r;
        int cc = n0 + wn + nt * 16 + row;
        float v = acc[mt][nt][r];
        if (OUT_BF16) ((u16*)Cout)[(size_t)rr * N + cc] = f2bf(v);
        else          ((float*)Cout)[(size_t)rr * N + cc] = v;
      }
}

// ---------------- LayerNorm + interleaved RoPE on kp -> K (bf16) ----------------
// One wave per token; lane owns dims (2*lane, 2*lane+1). RoPE pairs = (2p,2p+1), p<32.
__global__ __launch_bounds__(64) void lnrope_kernel(const float* __restrict__ kp,
    const float* __restrict__ cosb, const float* __restrict__ sinb,
    const float* __restrict__ gam, const float* __restrict__ bet,
    u16* __restrict__ Kout){
  int tok = blockIdx.x, lane = threadIdx.x;
  float v0 = kp[tok * 128 + 2 * lane];
  float v1 = kp[tok * 128 + 2 * lane + 1];
  float s = v0 + v1;
  #pragma unroll
  for (int m = 1; m < 64; m <<= 1) s += __shfl_xor(s, m);
  float mu = s * (1.f / 128.f);
  float d0 = v0 - mu, d1 = v1 - mu;
  float sq = d0 * d0 + d1 * d1;
  #pragma unroll
  for (int m = 1; m < 64; m <<= 1) sq += __shfl_xor(sq, m);
  float rs = rsqrtf(sq * (1.f / 128.f) + 1e-6f);
  float kn0 = d0 * rs * gam[2 * lane]     + bet[2 * lane];
  float kn1 = d1 * rs * gam[2 * lane + 1] + bet[2 * lane + 1];
  float o0 = kn0, o1 = kn1;
  if (lane < 32) {   // roped region: dims 0..63, pair p = lane
    float c  = cosb[tok * 64 + 2 * lane];
    float sn = sinb[tok * 64 + 2 * lane];
    o0 = kn0 * c - kn1 * sn;
    o1 = kn1 * c + kn0 * sn;
  }
  Kout[tok * 128 + 2 * lane]     = f2bf(o0);
  Kout[tok * 128 + 2 * lane + 1] = f2bf(o1);
}

// ---------------- in-place interleaved RoPE on Q's first 64 dims of each head ----------------
__global__ __launch_bounds__(256) void qrope_kernel(u16* __restrict__ Q,
    const float* __restrict__ cosb, const float* __restrict__ sinb){
  int idx = blockIdx.x * 256 + threadIdx.x;      // 2048 tok * 64 h * 32 pairs
  int p = idx & 31, h = (idx >> 5) & 63, tok = idx >> 11;
  size_t base = (size_t)tok * 8192 + h * 128 + 2 * p;
  u32 u = *(const u32*)(Q + base);
  float x1 = bf2f((u16)(u & 0xFFFF)), x2 = bf2f((u16)(u >> 16));
  float c = cosb[tok * 64 + 2 * p], s = sinb[tok * 64 + 2 * p];
  u16 o0 = f2bf(x1 * c - x2 * s);
  u16 o1 = f2bf(x2 * c + x1 * s);
  *(u32*)(Q + base) = (u32)o0 | ((u32)o1 << 16);
}

// ---------------- fused scores: out[b,q,k] = scale * sum_h w[b,q,h]*relu(Q_h . K) ----------------
// Block tile: 64 q x 128 k; K tile LDS-resident, B-frags preloaded in regs across h-loop.
__global__ __launch_bounds__(256) void attn_kernel(const u16* __restrict__ Q,
    const u16* __restrict__ Kb, const float* __restrict__ Wf, float* __restrict__ out){
  // swizzle: all 8 k-blocks of one (b,qt) land on the same XCD (blk%8 heuristic)
  int l = blockIdx.x;                   // 0..255
  int r_ = l & 7, j = (l >> 3) & 7, ph = l >> 6;
  int p  = r_ | (ph << 3);              // 0..31 = b*16+qt
  int b = p >> 4, qt = p & 15, kt = j;
  int q0 = qt * 64, k0 = kt * 128;

  const int tid = threadIdx.x, wave = tid >> 6, lane = tid & 63;
  const int row = lane & 15, quad = lane >> 4;
  const int wm = (wave >> 1) * 32;      // q offset of wave (0/32)
  const int wn = (wave & 1) * 64;       // k offset of wave (0/64)

  constexpr int LD = 136;               // 272 B stride: 16B-aligned, 2-way banks (free)
  __shared__ u16 Qs[64 * LD];
  __shared__ u16 Ks[128 * LD];

  // stage K tile once: 128 rows x 128 d
  #pragma unroll
  for (int c = 0; c < 8; ++c) {
    int idx = tid + c * 256;
    int rr = idx >> 4, kk = (idx & 15) * 8;
    *(uint4*)&Ks[rr * LD + kk] = *(const uint4*)(Kb + (size_t)(b * 1024 + k0 + rr) * 128 + kk);
  }
  __syncthreads();

  bf16x8 bfr[4][4];                     // [kstep][nt] — h-invariant, lives in regs
  #pragma unroll
  for (int ks = 0; ks < 4; ++ks)
    #pragma unroll
    for (int nt = 0; nt < 4; ++nt)
      bfr[ks][nt] = *(const bf16x8*)&Ks[(wn + nt * 16 + row) * LD + ks * 32 + quad * 8];

  const f32x4 zero = {0.f, 0.f, 0.f, 0.f};
  f32x4 sacc[2][4];
  #pragma unroll
  for (int mt = 0; mt < 2; ++mt)
    #pragma unroll
    for (int nt = 0; nt < 4; ++nt) sacc[mt][nt] = zero;

  for (int h = 0; h < 64; ++h) {
    __syncthreads();                    // protect Qs from overwrite while prior h computes
    #pragma unroll
    for (int c = 0; c < 4; ++c) {
      int idx = tid + c * 256;
      int rr = idx >> 4, kk = (idx & 15) * 8;
      *(uint4*)&Qs[rr * LD + kk] = *(const uint4*)(Q + (size_t)(b * 1024 + q0 + rr) * 8192 + h * 128 + kk);
    }
    __syncthreads();

    f32x4 lg[2][4];
    #pragma unroll
    for (int mt = 0; mt < 2; ++mt)
      #pragma unroll
      for (int nt = 0; nt < 4; ++nt) lg[mt][nt] = zero;
    #pragma unroll
    for (int ks = 0; ks < 4; ++ks) {
      bf16x8 af0 = *(const bf16x8*)&Qs[(wm +      row) * LD + ks * 32 + quad * 8];
      bf16x8 af1 = *(const bf16x8*)&Qs[(wm + 16 + row) * LD + ks * 32 + quad * 8];
      #pragma unroll
      for (int nt = 0; nt < 4; ++nt) {
        lg[0][nt] = __builtin_amdgcn_mfma_f32_16x16x32_bf16(af0, bfr[ks][nt], lg[0][nt], 0, 0, 0);
        lg[1][nt] = __builtin_amdgcn_mfma_f32_16x16x32_bf16(af1, bfr[ks][nt], lg[1][nt], 0, 0, 0);
      }
    }
    // epilogue: scores += w[q][h] * relu(logit)   (w loads broadcast within quad, L1-resident)
    float wv[2][4];
    #pragma unroll
    for (int mt = 0; mt < 2; ++mt)
      #pragma unroll
      for (int r = 0; r < 4; ++r)
        wv[mt][r] = Wf[(size_t)(b * 1024 + q0 + wm + mt * 16 + quad * 4 + r) * 64 + h];
    #pragma unroll
    for (int mt = 0; mt < 2; ++mt)
      #pragma unroll
      for (int nt = 0; nt < 4; ++nt)
        #pragma unroll
        for (int r = 0; r < 4; ++r)
          sacc[mt][nt][r] += wv[mt][r] * fmaxf(lg[mt][nt][r], 0.f);
  }

  const float scale = 0.088388347648318447f;   // 128^-0.5
  #pragma unroll
  for (int mt = 0; mt < 2; ++mt)
    #pragma unroll
    for (int nt = 0; nt < 4; ++nt)
      #pragma unroll
      for (int r = 0; r < 4; ++r) {
        int qq = q0 + wm + mt * 16 + quad * 4 + r;
        int kk = k0 + wn + nt * 16 + row;
        out[((size_t)b << 20) + (size_t)qq * 1024 + kk] = scale * sacc[mt][nt][r];
      }
}

extern "C" void kernel_launch(void* const* d_in, const int* in_sizes, int n_in,
                              void* d_out, int out_size, void* d_ws, size_t ws_size,
                              hipStream_t stream) {
  const float* x    = (const float*)d_in[0];   // [2048][7168] f32
  const float* qr   = (const float*)d_in[1];   // [2048][1536] f32
  const float* cosb = (const float*)d_in[2];   // [2048][64]   f32
  const float* sinb = (const float*)d_in[3];   // [2048][64]   f32
  const float* wq   = (const float*)d_in[4];   // [1536][8192] f32
  const float* wk   = (const float*)d_in[5];   // [7168][128]  f32
  const float* wp   = (const float*)d_in[6];   // [7168][64]   f32
  const float* gam  = (const float*)d_in[7];   // [128] f32
  const float* bet  = (const float*)d_in[8];   // [128] f32
  float* out = (float*)d_out;                  // [2][1024][1024] f32

  char* ws = (char*)d_ws;
  u16*   wqT = (u16*)(ws + 0);             // [8192][1536] bf16  25,165,824 B
  u16*   wkT = (u16*)(ws + 25165824);      // [128][7168]  bf16   1,835,008 B
  u16*   wpT = (u16*)(ws + 27000832);      // [64][7168]   bf16     917,504 B
  float* kp  = (float*)(ws + 27918336);    // [2048][128] f32     1,048,576 B
  float* Wf  = (float*)(ws + 28966912);    // [2048][64]  f32       524,288 B
  u16*   Kbf = (u16*)(ws + 29491200);      // [2048][128] bf16      524,288 B
  u16*   Qbf = (u16*)(ws + 30015488);      // [2048][8192] bf16  33,554,432 B  (end ~63.6 MB)

  (void)in_sizes; (void)n_in; (void)out_size; (void)ws_size;

  transpose_f32_bf16<<<dim3(8192 / 32, 1536 / 32), 256, 0, stream>>>(wq, wqT, 1536, 8192);
  transpose_f32_bf16<<<dim3(128 / 32, 7168 / 32), 256, 0, stream>>>(wk, wkT, 7168, 128);
  transpose_f32_bf16<<<dim3(64 / 32, 7168 / 32), 256, 0, stream>>>(wp, wpT, 7168, 64);

  gemm_bt<64, 64, true, false><<<dim3(2, 32), 256, 0, stream>>>(x, wkT, kp, 2048, 128, 7168);
  gemm_bt<64, 64, true, false><<<dim3(1, 32), 256, 0, stream>>>(x, wpT, Wf, 2048, 64, 7168);
  lnrope_kernel<<<2048, 64, 0, stream>>>(kp, cosb, sinb, gam, bet, Kbf);

  gemm_bt<128, 128, true, true><<<dim3(8192 / 128, 2048 / 128), 256, 0, stream>>>(qr, wqT, Qbf, 2048, 8192, 1536);
  qrope_kernel<<<16384, 256, 0, stream>>>(Qbf, cosb, sinb);

  attn_kernel<<<256, 256, 0, stream>>>(Qbf, Kbf, Wf, out);
}

// Round 3
// 342.539 us; speedup vs baseline: 2.2768x; 2.2768x over previous
//
#include <hip/hip_runtime.h>

typedef unsigned short u16;
typedef unsigned int   u32;

typedef __bf16 bf16x8 __attribute__((ext_vector_type(8)));
typedef float  f32x4  __attribute__((ext_vector_type(4)));

__device__ __forceinline__ float bf2f(u16 u){ u32 x = ((u32)u) << 16; return __builtin_bit_cast(float, x); }
__device__ __forceinline__ u16 f2bf(float f){
  u32 u = __builtin_bit_cast(u32, f);
  u32 r = (u + 0x7FFFu + ((u >> 16) & 1u)) >> 16;
  return (u16)r;
}
// pack bf16(a) into low16, bf16(b) into high16 (round-half-up via +0x8000, then v_perm)
__device__ __forceinline__ u32 pk2bf(float a, float b){
  u32 ua = __builtin_bit_cast(u32, a) + 0x8000u;
  u32 ub = __builtin_bit_cast(u32, b) + 0x8000u;
  return __builtin_amdgcn_perm(ub, ua, 0x07060302u);
}
// async global->LDS, 16B per lane; lds base must be wave-uniform
__device__ __forceinline__ void glds16(const void* g, void* l){
  __builtin_amdgcn_global_load_lds((const __attribute__((address_space(1))) void*)g,
                                   (__attribute__((address_space(3))) void*)l, 16, 0, 0);
}

// ---------------- transpose + f32->bf16 cast: dst[c][r] = bf16(src[r][c]) ----------------
__global__ __launch_bounds__(256) void transpose_f32_bf16(const float* __restrict__ src,
                                                          u16* __restrict__ dst, int R, int C){
  __shared__ u16 tile[32][33];
  int c0 = blockIdx.x * 32, r0 = blockIdx.y * 32;
  int tx = threadIdx.x & 31, ty = threadIdx.x >> 5;
  #pragma unroll
  for (int i = ty; i < 32; i += 8) tile[i][tx] = f2bf(src[(size_t)(r0 + i) * C + (c0 + tx)]);
  __syncthreads();
  #pragma unroll
  for (int i = ty; i < 32; i += 8) dst[(size_t)(c0 + i) * R + (r0 + tx)] = tile[tx][i];
}

// ---------------- f32 -> bf16 bulk convert (8 elems/thread) ----------------
__global__ __launch_bounds__(256) void cvt_f32_bf16(const float* __restrict__ src,
                                                    u16* __restrict__ dst){
  size_t i = ((size_t)blockIdx.x * 256 + threadIdx.x) * 8;
  const float4* a4 = (const float4*)(src + i);
  float4 f0 = a4[0], f1 = a4[1];
  u32 w[4] = { pk2bf(f0.x, f0.y), pk2bf(f0.z, f0.w), pk2bf(f1.x, f1.y), pk2bf(f1.z, f1.w) };
  *(uint4*)(dst + i) = *(const uint4*)w;
}

// ---------------- split-K projection: P[s][m][0..191] = x[m][ks] @ [wk;wp][ks] ----------------
// grid (16 slabs, 32 mblk), 256 thr. Slab = 448 K (7 steps of BK=64).
__global__ __launch_bounds__(256) void proj_splitk(const float* __restrict__ X,
    const u16* __restrict__ BT, float* __restrict__ P){
  constexpr int Kf = 7168;
  const int s = blockIdx.x, m0 = blockIdx.y * 64;
  const int kbase = s * 448;
  __shared__ u16 As[2 * 64 * 36];      // [kc][64][36] padded
  __shared__ u16 Bs[2 * 192 * 32];     // [kc][192][32] unpadded (glds)
  const int tid = threadIdx.x, wave = tid >> 6, lane = tid & 63;
  const int row = lane & 15, quad = lane >> 4;
  const int wm = (wave & 1) * 32, wn = (wave >> 1) * 96;

  const f32x4 zero = {0.f, 0.f, 0.f, 0.f};
  f32x4 acc[2][6];
  #pragma unroll
  for (int mt = 0; mt < 2; ++mt)
    #pragma unroll
    for (int nt = 0; nt < 6; ++nt) acc[mt][nt] = zero;

  for (int kb = 0; kb < 7; ++kb) {
    int k0 = kbase + kb * 64;
    // B: 24 glds chunks (1024B each), 6 per wave
    #pragma unroll
    for (int c = 0; c < 6; ++c) {
      int chunk = wave * 6 + c;
      int kc = chunk / 12, rem = chunk % 12;
      int r = rem * 16 + (lane >> 2), col = (lane & 3) * 8;
      glds16(BT + (size_t)r * Kf + k0 + kc * 32 + col, (void*)&Bs[chunk * 512]);
    }
    // A: 64x64 f32 -> bf16, 16 f32/thread
    #pragma unroll
    for (int c = 0; c < 2; ++c) {
      int idx = tid + c * 256;
      int r = idx >> 3, kf = (idx & 7) * 8;
      const float4* ap = (const float4*)(X + (size_t)(m0 + r) * Kf + k0 + kf);
      float4 f0 = ap[0], f1 = ap[1];
      u32 w[4] = { pk2bf(f0.x, f0.y), pk2bf(f0.z, f0.w), pk2bf(f1.x, f1.y), pk2bf(f1.z, f1.w) };
      *(uint4*)&As[(kf >> 5) * 2304 + r * 36 + (kf & 31)] = *(const uint4*)w;
    }
    __syncthreads();
    #pragma unroll
    for (int ks = 0; ks < 2; ++ks) {
      bf16x8 af[2], bfr[6];
      #pragma unroll
      for (int mt = 0; mt < 2; ++mt) af[mt] = *(const bf16x8*)&As[ks * 2304 + (wm + mt * 16 + row) * 36 + quad * 8];
      #pragma unroll
      for (int nt = 0; nt < 6; ++nt) bfr[nt] = *(const bf16x8*)&Bs[ks * 6144 + (wn + nt * 16 + row) * 32 + quad * 8];
      #pragma unroll
      for (int mt = 0; mt < 2; ++mt)
        #pragma unroll
        for (int nt = 0; nt < 6; ++nt)
          acc[mt][nt] = __builtin_amdgcn_mfma_f32_16x16x32_bf16(af[mt], bfr[nt], acc[mt][nt], 0, 0, 0);
    }
    __syncthreads();
  }
  #pragma unroll
  for (int mt = 0; mt < 2; ++mt)
    #pragma unroll
    for (int nt = 0; nt < 6; ++nt)
      #pragma unroll
      for (int r = 0; r < 4; ++r) {
        int rr = m0 + wm + mt * 16 + quad * 4 + r;
        int cc = wn + nt * 16 + row;
        P[((size_t)s * 2048 + rr) * 192 + cc] = acc[mt][nt][r];
      }
}

// ---------------- reduce 16 partials + LayerNorm + RoPE -> Kbf (bf16), Wf (f32) ----------------
__global__ __launch_bounds__(64) void reduce_lnrope(const float* __restrict__ P,
    const float* __restrict__ cosb, const float* __restrict__ sinb,
    const float* __restrict__ gam, const float* __restrict__ bet,
    u16* __restrict__ Kout, float* __restrict__ Wout){
  int tok = blockIdx.x, lane = threadIdx.x;
  float v0 = 0.f, v1 = 0.f, w = 0.f;
  #pragma unroll
  for (int s = 0; s < 16; ++s) {
    const float* p = P + ((size_t)s * 2048 + tok) * 192;
    v0 += p[2 * lane]; v1 += p[2 * lane + 1]; w += p[128 + lane];
  }
  Wout[tok * 64 + lane] = w;
  float sm = v0 + v1;
  #pragma unroll
  for (int m = 1; m < 64; m <<= 1) sm += __shfl_xor(sm, m);
  float mu = sm * (1.f / 128.f);
  float d0 = v0 - mu, d1 = v1 - mu;
  float sq = d0 * d0 + d1 * d1;
  #pragma unroll
  for (int m = 1; m < 64; m <<= 1) sq += __shfl_xor(sq, m);
  float rs = rsqrtf(sq * (1.f / 128.f) + 1e-6f);
  float kn0 = d0 * rs * gam[2 * lane]     + bet[2 * lane];
  float kn1 = d1 * rs * gam[2 * lane + 1] + bet[2 * lane + 1];
  float o0 = kn0, o1 = kn1;
  if (lane < 32) {
    float c  = cosb[tok * 64 + 2 * lane];
    float sn = sinb[tok * 64 + 2 * lane];
    o0 = kn0 * c - kn1 * sn;
    o1 = kn1 * c + kn0 * sn;
  }
  Kout[tok * 128 + 2 * lane]     = f2bf(o0);
  Kout[tok * 128 + 2 * lane + 1] = f2bf(o1);
}

// ---------------- Q-GEMM (M=2048,N=8192,K=1536) + fused interleaved RoPE epilogue ----------------
template<bool AGLDS>
__global__ __launch_bounds__(256) void qgemm(const void* __restrict__ Aptr,
    const u16* __restrict__ BT, const float* __restrict__ cosb,
    const float* __restrict__ sinb, u16* __restrict__ Qout){
  constexpr int K = 1536, N = 8192;
  constexpr int LDA = AGLDS ? 32 : 40;
  __shared__ u16 As[128 * LDA];
  __shared__ u16 Bs[128 * 32];
  const int tid = threadIdx.x, wave = tid >> 6, lane = tid & 63;
  const int row = lane & 15, quad = lane >> 4;
  const int wm = (wave >> 1) * 64, wn = (wave & 1) * 64;
  const int m0 = blockIdx.y * 128, n0 = blockIdx.x * 128;

  const f32x4 zero = {0.f, 0.f, 0.f, 0.f};
  f32x4 acc[4][4];
  #pragma unroll
  for (int mt = 0; mt < 4; ++mt)
    #pragma unroll
    for (int nt = 0; nt < 4; ++nt) acc[mt][nt] = zero;

  for (int k0 = 0; k0 < K; k0 += 32) {
    #pragma unroll
    for (int c = 0; c < 2; ++c) {            // B: 8 glds chunks, 2/wave
      int chunk = wave * 2 + c;
      int r = chunk * 16 + (lane >> 2), col = (lane & 3) * 8;
      glds16(BT + (size_t)(n0 + r) * K + k0 + col, (void*)&Bs[chunk * 512]);
    }
    if (AGLDS) {
      #pragma unroll
      for (int c = 0; c < 2; ++c) {
        int chunk = wave * 2 + c;
        int r = chunk * 16 + (lane >> 2), col = (lane & 3) * 8;
        glds16((const u16*)Aptr + (size_t)(m0 + r) * K + k0 + col, (void*)&As[chunk * 512]);
      }
    } else {
      #pragma unroll
      for (int c = 0; c < 2; ++c) {          // A: f32 load + pack
        int idx = tid + c * 256;
        int r = idx >> 2, kk = (idx & 3) * 8;
        const float4* ap = (const float4*)((const float*)Aptr + (size_t)(m0 + r) * K + k0 + kk);
        float4 f0 = ap[0], f1 = ap[1];
        u32 w[4] = { pk2bf(f0.x, f0.y), pk2bf(f0.z, f0.w), pk2bf(f1.x, f1.y), pk2bf(f1.z, f1.w) };
        *(uint4*)&As[r * LDA + kk] = *(const uint4*)w;
      }
    }
    __syncthreads();
    bf16x8 af[4], bfr[4];
    #pragma unroll
    for (int mt = 0; mt < 4; ++mt) af[mt]  = *(const bf16x8*)&As[(wm + mt * 16 + row) * LDA + quad * 8];
    #pragma unroll
    for (int nt = 0; nt < 4; ++nt) bfr[nt] = *(const bf16x8*)&Bs[(wn + nt * 16 + row) * 32 + quad * 8];
    #pragma unroll
    for (int mt = 0; mt < 4; ++mt)
      #pragma unroll
      for (int nt = 0; nt < 4; ++nt)
        acc[mt][nt] = __builtin_amdgcn_mfma_f32_16x16x32_bf16(af[mt], bfr[nt], acc[mt][nt], 0, 0, 0);
    __syncthreads();
  }

  // epilogue: RoPE on head dims 0..63 (wave-uniform: wn==0 waves only), then store bf16
  const bool roped = (wn == 0);
  #pragma unroll
  for (int mt = 0; mt < 4; ++mt)
    #pragma unroll
    for (int nt = 0; nt < 4; ++nt)
      #pragma unroll
      for (int r = 0; r < 4; ++r) {
        int rr = m0 + wm + mt * 16 + quad * 4 + r;
        int cc = n0 + wn + nt * 16 + row;
        float v = acc[mt][nt][r];
        float o = v;
        if (roped) {
          int hd = (wn + nt * 16 + row) & 127;          // 0..63 here
          float c = cosb[rr * 64 + hd];
          float s = sinb[rr * 64 + hd];
          float vo = __shfl_xor(v, 1);                   // partner col (cc^1), same row
          o = (cc & 1) ? (v * c + vo * s) : (v * c - vo * s);
        }
        Qout[(size_t)rr * N + cc] = f2bf(o);
      }
}

// ---------------- fused scores with h-split: out += scale * sum_{h in half} w*relu(QK^T) ----------------
__global__ __launch_bounds__(256) void attn_kernel(const u16* __restrict__ Q,
    const u16* __restrict__ Kb, const float* __restrict__ Wf, float* __restrict__ out){
  int blk = blockIdx.x;                       // 512 blocks
  int x = blk & 7, kt = (blk >> 3) & 7, hs = (blk >> 6) & 1, g = (blk >> 7) & 3;
  int p = x + 8 * g;                          // 0..31
  int b = p >> 4, qt = p & 15;
  int q0 = qt * 64, k0 = kt * 128;

  const int tid = threadIdx.x, wave = tid >> 6, lane = tid & 63;
  const int row = lane & 15, quad = lane >> 4;
  const int wm = (wave >> 1) * 32;            // q offset (0/32)
  const int wn = (wave & 1) * 64;             // k offset (0/64)

  __shared__ u16 Ks[128 * 136];               // padded: frag reads once
  __shared__ u16 Qs[4 * 64 * 32];             // [kc][row][32] unpadded (glds)

  #pragma unroll
  for (int c = 0; c < 8; ++c) {
    int idx = tid + c * 256;
    int rr = idx >> 4, kk = (idx & 15) * 8;
    *(uint4*)&Ks[rr * 136 + kk] = *(const uint4*)(Kb + (size_t)(b * 1024 + k0 + rr) * 128 + kk);
  }
  __syncthreads();

  bf16x8 bfr[4][4];                           // h-invariant K fragments
  #pragma unroll
  for (int ks = 0; ks < 4; ++ks)
    #pragma unroll
    for (int nt = 0; nt < 4; ++nt)
      bfr[ks][nt] = *(const bf16x8*)&Ks[(wn + nt * 16 + row) * 136 + ks * 32 + quad * 8];

  const f32x4 zero = {0.f, 0.f, 0.f, 0.f};
  f32x4 sacc[2][4];
  #pragma unroll
  for (int mt = 0; mt < 2; ++mt)
    #pragma unroll
    for (int nt = 0; nt < 4; ++nt) sacc[mt][nt] = zero;

  for (int hi = 0; hi < 32; ++hi) {
    int h = hs * 32 + hi;
    __syncthreads();
    #pragma unroll
    for (int c = 0; c < 4; ++c) {             // Q tile 64x128 via glds into [kc][r][32]
      int chunk = wave * 4 + c;
      int kc = chunk >> 2, rg = chunk & 3;
      glds16(Q + (size_t)(b * 1024 + q0 + rg * 16 + (lane >> 2)) * 8192 + h * 128 + kc * 32 + (lane & 3) * 8,
             (void*)&Qs[chunk * 512]);
    }
    __syncthreads();

    f32x4 lg[2][4];
    #pragma unroll
    for (int mt = 0; mt < 2; ++mt)
      #pragma unroll
      for (int nt = 0; nt < 4; ++nt) lg[mt][nt] = zero;
    #pragma unroll
    for (int ks = 0; ks < 4; ++ks) {
      bf16x8 af0 = *(const bf16x8*)&Qs[ks * 2048 + (wm +      row) * 32 + quad * 8];
      bf16x8 af1 = *(const bf16x8*)&Qs[ks * 2048 + (wm + 16 + row) * 32 + quad * 8];
      #pragma unroll
      for (int nt = 0; nt < 4; ++nt) {
        lg[0][nt] = __builtin_amdgcn_mfma_f32_16x16x32_bf16(af0, bfr[ks][nt], lg[0][nt], 0, 0, 0);
        lg[1][nt] = __builtin_amdgcn_mfma_f32_16x16x32_bf16(af1, bfr[ks][nt], lg[1][nt], 0, 0, 0);
      }
    }
    float wv[2][4];
    #pragma unroll
    for (int mt = 0; mt < 2; ++mt)
      #pragma unroll
      for (int r = 0; r < 4; ++r)
        wv[mt][r] = Wf[(size_t)(b * 1024 + q0 + wm + mt * 16 + quad * 4 + r) * 64 + h];
    #pragma unroll
    for (int mt = 0; mt < 2; ++mt)
      #pragma unroll
      for (int nt = 0; nt < 4; ++nt)
        #pragma unroll
        for (int r = 0; r < 4; ++r)
          sacc[mt][nt][r] += wv[mt][r] * fmaxf(lg[mt][nt][r], 0.f);
  }

  const float scale = 0.088388347648318447f;  // 128^-0.5
  #pragma unroll
  for (int mt = 0; mt < 2; ++mt)
    #pragma unroll
    for (int nt = 0; nt < 4; ++nt)
      #pragma unroll
      for (int r = 0; r < 4; ++r) {
        int qq = q0 + wm + mt * 16 + quad * 4 + r;
        int kk = k0 + wn + nt * 16 + row;
        unsafeAtomicAdd(&out[((size_t)b << 20) + (size_t)qq * 1024 + kk], scale * sacc[mt][nt][r]);
      }
}

extern "C" void kernel_launch(void* const* d_in, const int* in_sizes, int n_in,
                              void* d_out, int out_size, void* d_ws, size_t ws_size,
                              hipStream_t stream) {
  const float* x    = (const float*)d_in[0];   // [2048][7168]
  const float* qr   = (const float*)d_in[1];   // [2048][1536]
  const float* cosb = (const float*)d_in[2];   // [2048][64]
  const float* sinb = (const float*)d_in[3];   // [2048][64]
  const float* wq   = (const float*)d_in[4];   // [1536][8192]
  const float* wk   = (const float*)d_in[5];   // [7168][128]
  const float* wp   = (const float*)d_in[6];   // [7168][64]
  const float* gam  = (const float*)d_in[7];   // [128]
  const float* bet  = (const float*)d_in[8];   // [128]
  float* out = (float*)d_out;                  // [2][1024][1024] f32

  char* ws = (char*)d_ws;
  float* P    = (float*)(ws + 0);          // [16][2048][192] f32 = 25,165,824 B (proj phase)
  u16*   wqT  = (u16*)(ws + 0);            // [8192][1536] bf16 (after reduce; same region)
  u16*   wkwpT= (u16*)(ws + 25165824);     // [192][7168] bf16 = 2,752,512 B
  float* Wf   = (float*)(ws + 27918336);   // [2048][64] f32 = 524,288 B
  u16*   Kbf  = (u16*)(ws + 28442624);     // [2048][128] bf16 = 524,288 B
  u16*   Qbf  = (u16*)(ws + 28966912);     // [2048][8192] bf16 = 33,554,432 B -> 62,521,344
  const size_t QRB_OFF = 62521344;
  u16*   qrb  = (u16*)(ws + QRB_OFF);      // [2048][1536] bf16 = 6,291,456 B -> 68,812,800
  const bool big_ws = (ws_size >= (size_t)68812800);

  (void)in_sizes; (void)n_in;

  hipMemsetAsync(d_out, 0, (size_t)out_size * 4, stream);

  transpose_f32_bf16<<<dim3(4, 224),  256, 0, stream>>>(wk, wkwpT,              7168, 128);
  transpose_f32_bf16<<<dim3(2, 224),  256, 0, stream>>>(wp, wkwpT + 128 * 7168, 7168, 64);

  proj_splitk<<<dim3(16, 32), 256, 0, stream>>>(x, wkwpT, P);
  reduce_lnrope<<<2048, 64, 0, stream>>>(P, cosb, sinb, gam, bet, Kbf, Wf);

  transpose_f32_bf16<<<dim3(256, 48), 256, 0, stream>>>(wq, wqT, 1536, 8192);

  if (big_ws) {
    cvt_f32_bf16<<<1536, 256, 0, stream>>>(qr, qrb);
    qgemm<true><<<dim3(64, 16), 256, 0, stream>>>(qrb, wqT, cosb, sinb, Qbf);
  } else {
    qgemm<false><<<dim3(64, 16), 256, 0, stream>>>(qr, wqT, cosb, sinb, Qbf);
  }

  attn_kernel<<<512, 256, 0, stream>>>(Qbf, Kbf, Wf, out);
}

// Round 4
// 333.840 us; speedup vs baseline: 2.3361x; 1.0261x over previous
//
#include <hip/hip_runtime.h>

typedef unsigned short u16;
typedef unsigned int   u32;

typedef __bf16 bf16x8 __attribute__((ext_vector_type(8)));
typedef float  f32x4  __attribute__((ext_vector_type(4)));

__device__ __forceinline__ float bf2f(u16 u){ u32 x = ((u32)u) << 16; return __builtin_bit_cast(float, x); }
__device__ __forceinline__ u16 f2bf(float f){
  u32 u = __builtin_bit_cast(u32, f);
  u32 r = (u + 0x7FFFu + ((u >> 16) & 1u)) >> 16;
  return (u16)r;
}
// pack bf16(a) low16, bf16(b) high16
__device__ __forceinline__ u32 pk2bf(float a, float b){
  u32 ua = __builtin_bit_cast(u32, a) + 0x8000u;
  u32 ub = __builtin_bit_cast(u32, b) + 0x8000u;
  return __builtin_amdgcn_perm(ub, ua, 0x07060302u);
}
// async global->LDS, 16B/lane; lds base wave-uniform, dest = base + lane*16
__device__ __forceinline__ void glds16(const void* g, void* l){
  __builtin_amdgcn_global_load_lds((const __attribute__((address_space(1))) void*)g,
                                   (__attribute__((address_space(3))) void*)l, 16, 0, 0);
}

// ---------------- transpose + f32->bf16 cast: dst[c][r] = bf16(src[r][c]) ----------------
__global__ __launch_bounds__(256) void transpose_f32_bf16(const float* __restrict__ src,
                                                          u16* __restrict__ dst, int R, int C){
  __shared__ u16 tile[32][33];
  int c0 = blockIdx.x * 32, r0 = blockIdx.y * 32;
  int tx = threadIdx.x & 31, ty = threadIdx.x >> 5;
  #pragma unroll
  for (int i = ty; i < 32; i += 8) tile[i][tx] = f2bf(src[(size_t)(r0 + i) * C + (c0 + tx)]);
  __syncthreads();
  #pragma unroll
  for (int i = ty; i < 32; i += 8) dst[(size_t)(c0 + i) * R + (r0 + tx)] = tile[tx][i];
}

// ---------------- f32 -> bf16 bulk convert (8 elems/thread) ----------------
__global__ __launch_bounds__(256) void cvt_f32_bf16(const float* __restrict__ src,
                                                    u16* __restrict__ dst){
  size_t i = ((size_t)blockIdx.x * 256 + threadIdx.x) * 8;
  const float4* a4 = (const float4*)(src + i);
  float4 f0 = a4[0], f1 = a4[1];
  u32 w[4] = { pk2bf(f0.x, f0.y), pk2bf(f0.z, f0.w), pk2bf(f1.x, f1.y), pk2bf(f1.z, f1.w) };
  *(uint4*)(dst + i) = *(const uint4*)w;
}

// ---------------- split-K projection: P[s][m][0..191] = x[m][ks] @ [wk;wp][ks] ----------------
__global__ __launch_bounds__(256) void proj_splitk(const float* __restrict__ X,
    const u16* __restrict__ BT, float* __restrict__ P){
  constexpr int Kf = 7168;
  const int s = blockIdx.x, m0 = blockIdx.y * 64;
  const int kbase = s * 448;
  __shared__ u16 As[2 * 64 * 36];      // [kc][64][36] padded (VALU-packed stores)
  __shared__ u16 Bs[2 * 192 * 32];     // [kc][192][32] unpadded (glds)
  const int tid = threadIdx.x, wave = tid >> 6, lane = tid & 63;
  const int row = lane & 15, quad = lane >> 4;
  const int wm = (wave & 1) * 32, wn = (wave >> 1) * 96;

  const f32x4 zero = {0.f, 0.f, 0.f, 0.f};
  f32x4 acc[2][6];
  #pragma unroll
  for (int mt = 0; mt < 2; ++mt)
    #pragma unroll
    for (int nt = 0; nt < 6; ++nt) acc[mt][nt] = zero;

  for (int kb = 0; kb < 7; ++kb) {
    int k0 = kbase + kb * 64;
    #pragma unroll
    for (int c = 0; c < 6; ++c) {
      int chunk = wave * 6 + c;
      int kc = chunk / 12, rem = chunk % 12;
      int r = rem * 16 + (lane >> 2), col = (lane & 3) * 8;
      glds16(BT + (size_t)r * Kf + k0 + kc * 32 + col, (void*)&Bs[chunk * 512]);
    }
    #pragma unroll
    for (int c = 0; c < 2; ++c) {
      int idx = tid + c * 256;
      int r = idx >> 3, kf = (idx & 7) * 8;
      const float4* ap = (const float4*)(X + (size_t)(m0 + r) * Kf + k0 + kf);
      float4 f0 = ap[0], f1 = ap[1];
      u32 w[4] = { pk2bf(f0.x, f0.y), pk2bf(f0.z, f0.w), pk2bf(f1.x, f1.y), pk2bf(f1.z, f1.w) };
      *(uint4*)&As[(kf >> 5) * 2304 + r * 36 + (kf & 31)] = *(const uint4*)w;
    }
    __syncthreads();
    #pragma unroll
    for (int ks = 0; ks < 2; ++ks) {
      bf16x8 af[2], bfr[6];
      #pragma unroll
      for (int mt = 0; mt < 2; ++mt) af[mt] = *(const bf16x8*)&As[ks * 2304 + (wm + mt * 16 + row) * 36 + quad * 8];
      #pragma unroll
      for (int nt = 0; nt < 6; ++nt) bfr[nt] = *(const bf16x8*)&Bs[ks * 6144 + (wn + nt * 16 + row) * 32 + quad * 8];
      #pragma unroll
      for (int mt = 0; mt < 2; ++mt)
        #pragma unroll
        for (int nt = 0; nt < 6; ++nt)
          acc[mt][nt] = __builtin_amdgcn_mfma_f32_16x16x32_bf16(af[mt], bfr[nt], acc[mt][nt], 0, 0, 0);
    }
    __syncthreads();
  }
  #pragma unroll
  for (int mt = 0; mt < 2; ++mt)
    #pragma unroll
    for (int nt = 0; nt < 6; ++nt)
      #pragma unroll
      for (int r = 0; r < 4; ++r) {
        int rr = m0 + wm + mt * 16 + quad * 4 + r;
        int cc = wn + nt * 16 + row;
        P[((size_t)s * 2048 + rr) * 192 + cc] = acc[mt][nt][r];
      }
}

// ---------------- reduce 16 partials + LayerNorm + RoPE -> Kbf (bf16), WT (f32, [h][tok]) ----------------
__global__ __launch_bounds__(64) void reduce_lnrope(const float* __restrict__ P,
    const float* __restrict__ cosb, const float* __restrict__ sinb,
    const float* __restrict__ gam, const float* __restrict__ bet,
    u16* __restrict__ Kout, float* __restrict__ WoutT){
  int tok = blockIdx.x, lane = threadIdx.x;
  float v0 = 0.f, v1 = 0.f, w = 0.f;
  #pragma unroll
  for (int s = 0; s < 16; ++s) {
    const float* p = P + ((size_t)s * 2048 + tok) * 192;
    v0 += p[2 * lane]; v1 += p[2 * lane + 1]; w += p[128 + lane];
  }
  WoutT[(size_t)lane * 2048 + tok] = w;     // transposed: [h][tok]
  float sm = v0 + v1;
  #pragma unroll
  for (int m = 1; m < 64; m <<= 1) sm += __shfl_xor(sm, m);
  float mu = sm * (1.f / 128.f);
  float d0 = v0 - mu, d1 = v1 - mu;
  float sq = d0 * d0 + d1 * d1;
  #pragma unroll
  for (int m = 1; m < 64; m <<= 1) sq += __shfl_xor(sq, m);
  float rs = rsqrtf(sq * (1.f / 128.f) + 1e-6f);
  float kn0 = d0 * rs * gam[2 * lane]     + bet[2 * lane];
  float kn1 = d1 * rs * gam[2 * lane + 1] + bet[2 * lane + 1];
  float o0 = kn0, o1 = kn1;
  if (lane < 32) {
    float c  = cosb[tok * 64 + 2 * lane];
    float sn = sinb[tok * 64 + 2 * lane];
    o0 = kn0 * c - kn1 * sn;
    o1 = kn1 * c + kn0 * sn;
  }
  Kout[tok * 128 + 2 * lane]     = f2bf(o0);
  Kout[tok * 128 + 2 * lane + 1] = f2bf(o1);
}

// ---------------- Q-GEMM (M=2048,N=8192,K=1536), BK=64, fused RoPE epilogue ----------------
template<bool AGLDS>
__global__ __launch_bounds__(256) void qgemm(const void* __restrict__ Aptr,
    const u16* __restrict__ BT, const float* __restrict__ cosb,
    const float* __restrict__ sinb, u16* __restrict__ Qout){
  constexpr int K = 1536, N = 8192;
  __shared__ u16 As[2 * 128 * 32];   // [kc][128][32] unpadded (glds / packed stores)
  __shared__ u16 Bs[2 * 128 * 32];
  const int tid = threadIdx.x, wave = tid >> 6, lane = tid & 63;
  const int row = lane & 15, quad = lane >> 4;
  const int wm = (wave >> 1) * 64, wn = (wave & 1) * 64;
  const int m0 = blockIdx.y * 128, n0 = blockIdx.x * 128;

  const f32x4 zero = {0.f, 0.f, 0.f, 0.f};
  f32x4 acc[4][4];
  #pragma unroll
  for (int mt = 0; mt < 4; ++mt)
    #pragma unroll
    for (int nt = 0; nt < 4; ++nt) acc[mt][nt] = zero;

  for (int k0 = 0; k0 < K; k0 += 64) {
    #pragma unroll
    for (int c = 0; c < 4; ++c) {            // B: 16 chunks (1024B), 4/wave
      int chunk = wave * 4 + c;
      int kc = chunk >> 3, rg = chunk & 7;
      int r = rg * 16 + (lane >> 2), col = kc * 32 + (lane & 3) * 8;
      glds16(BT + (size_t)(n0 + r) * K + k0 + col, (void*)&Bs[chunk * 512]);
    }
    if (AGLDS) {
      #pragma unroll
      for (int c = 0; c < 4; ++c) {
        int chunk = wave * 4 + c;
        int kc = chunk >> 3, rg = chunk & 7;
        int r = rg * 16 + (lane >> 2), col = kc * 32 + (lane & 3) * 8;
        glds16((const u16*)Aptr + (size_t)(m0 + r) * K + k0 + col, (void*)&As[chunk * 512]);
      }
    } else {
      #pragma unroll
      for (int c = 0; c < 4; ++c) {          // A: f32 load + pack, 128x64
        int idx = tid + c * 256;
        int r = idx >> 3, kf = (idx & 7) * 8;
        const float4* ap = (const float4*)((const float*)Aptr + (size_t)(m0 + r) * K + k0 + kf);
        float4 f0 = ap[0], f1 = ap[1];
        u32 w[4] = { pk2bf(f0.x, f0.y), pk2bf(f0.z, f0.w), pk2bf(f1.x, f1.y), pk2bf(f1.z, f1.w) };
        *(uint4*)&As[(kf >> 5) * 4096 + r * 32 + (kf & 31)] = *(const uint4*)w;
      }
    }
    __syncthreads();
    #pragma unroll
    for (int kk = 0; kk < 2; ++kk) {
      bf16x8 af[4], bfr[4];
      #pragma unroll
      for (int mt = 0; mt < 4; ++mt) af[mt]  = *(const bf16x8*)&As[kk * 4096 + (wm + mt * 16 + row) * 32 + quad * 8];
      #pragma unroll
      for (int nt = 0; nt < 4; ++nt) bfr[nt] = *(const bf16x8*)&Bs[kk * 4096 + (wn + nt * 16 + row) * 32 + quad * 8];
      #pragma unroll
      for (int mt = 0; mt < 4; ++mt)
        #pragma unroll
        for (int nt = 0; nt < 4; ++nt)
          acc[mt][nt] = __builtin_amdgcn_mfma_f32_16x16x32_bf16(af[mt], bfr[nt], acc[mt][nt], 0, 0, 0);
    }
    __syncthreads();
  }

  // epilogue: RoPE on head dims 0..63 (wave-uniform), store bf16
  const bool roped = (wn == 0);
  #pragma unroll
  for (int mt = 0; mt < 4; ++mt)
    #pragma unroll
    for (int nt = 0; nt < 4; ++nt)
      #pragma unroll
      for (int r = 0; r < 4; ++r) {
        int rr = m0 + wm + mt * 16 + quad * 4 + r;
        int cc = n0 + wn + nt * 16 + row;
        float v = acc[mt][nt][r];
        float o = v;
        if (roped) {
          int hd = (wn + nt * 16 + row) & 127;
          float c = cosb[rr * 64 + hd];
          float s = sinb[rr * 64 + hd];
          float vo = __shfl_xor(v, 1);
          o = (cc & 1) ? (v * c + vo * s) : (v * c - vo * s);
        }
        Qout[(size_t)rr * N + cc] = f2bf(o);
      }
}

// ---------------- fused scores, h-split x2, 2 heads per barrier, shared LDS reuse ----------------
__global__ __launch_bounds__(256) void attn_kernel(const u16* __restrict__ Q,
    const u16* __restrict__ Kb, const float* __restrict__ WT, float* __restrict__ out){
  int blk = blockIdx.x;                       // 512 blocks
  int x = blk & 7, kt = (blk >> 3) & 7, hs = (blk >> 6) & 1, g4 = (blk >> 7) & 3;
  int p = x + 8 * g4;                         // 0..31
  int b = p >> 4, qt = p & 15;
  int q0 = qt * 64, k0 = kt * 128;

  const int tid = threadIdx.x, wave = tid >> 6, lane = tid & 63;
  const int row = lane & 15, quad = lane >> 4;
  const int wm = (wave >> 1) * 32;            // q offset (0/32)
  const int wn = (wave & 1) * 64;             // k offset (0/64)

  __shared__ u16 Sh[2 * 64 * 128];            // 32 KB: K tile first, then [2h][kc][r][32] Q tiles
  __shared__ float Ws[32 * 64];               // 8 KB: [h_local][q_local]

  // stage K tile 128x128 into Sh as [r][128]: 32 chunks, 8/wave
  #pragma unroll
  for (int c = 0; c < 8; ++c) {
    int g = wave * 8 + c;
    int rr = g * 4 + (lane >> 4), col = (lane & 15) * 8;
    glds16(Kb + (size_t)(b * 1024 + k0 + rr) * 128 + col, (void*)&Sh[g * 512]);
  }
  // stage W half: [32][64] f32 from WT[h][tok] (coalesced)
  {
    int hl = tid >> 3, qq = (tid & 7) * 8;
    const float* src = WT + (size_t)(hs * 32 + hl) * 2048 + b * 1024 + q0 + qq;
    *(float4*)&Ws[hl * 64 + qq]     = *(const float4*)src;
    *(float4*)&Ws[hl * 64 + qq + 4] = *(const float4*)(src + 4);
  }
  __syncthreads();

  bf16x8 bfr[4][4];                           // h-invariant K fragments (read once)
  #pragma unroll
  for (int ks = 0; ks < 4; ++ks)
    #pragma unroll
    for (int nt = 0; nt < 4; ++nt)
      bfr[ks][nt] = *(const bf16x8*)&Sh[(wn + nt * 16 + row) * 128 + ks * 32 + quad * 8];

  const f32x4 zero = {0.f, 0.f, 0.f, 0.f};
  f32x4 sacc[2][4];
  #pragma unroll
  for (int mt = 0; mt < 2; ++mt)
    #pragma unroll
    for (int nt = 0; nt < 4; ++nt) sacc[mt][nt] = zero;

  for (int hp = 0; hp < 16; ++hp) {
    int h0 = hs * 32 + hp * 2;
    __syncthreads();                          // prior compute done (and bfr reads at hp==0)
    #pragma unroll
    for (int c = 0; c < 8; ++c) {             // 2 Q tiles 64x128: 32 chunks, 8/wave
      int g = wave * 8 + c;
      int hsub = g >> 4, rem = g & 15;
      int kc = rem >> 2, rg = rem & 3;
      glds16(Q + (size_t)(b * 1024 + q0 + rg * 16 + (lane >> 2)) * 8192 + (h0 + hsub) * 128 + kc * 32 + (lane & 3) * 8,
             (void*)&Sh[hsub * 8192 + rem * 512]);
    }
    __syncthreads();

    #pragma unroll
    for (int hsub = 0; hsub < 2; ++hsub) {
      f32x4 lg[2][4];
      #pragma unroll
      for (int mt = 0; mt < 2; ++mt)
        #pragma unroll
        for (int nt = 0; nt < 4; ++nt) lg[mt][nt] = zero;
      #pragma unroll
      for (int ks = 0; ks < 4; ++ks) {
        bf16x8 af0 = *(const bf16x8*)&Sh[hsub * 8192 + ks * 2048 + (wm +      row) * 32 + quad * 8];
        bf16x8 af1 = *(const bf16x8*)&Sh[hsub * 8192 + ks * 2048 + (wm + 16 + row) * 32 + quad * 8];
        #pragma unroll
        for (int nt = 0; nt < 4; ++nt) {
          lg[0][nt] = __builtin_amdgcn_mfma_f32_16x16x32_bf16(af0, bfr[ks][nt], lg[0][nt], 0, 0, 0);
          lg[1][nt] = __builtin_amdgcn_mfma_f32_16x16x32_bf16(af1, bfr[ks][nt], lg[1][nt], 0, 0, 0);
        }
      }
      int hl = hp * 2 + hsub;
      f32x4 w0 = *(const f32x4*)&Ws[hl * 64 + wm +      quad * 4];
      f32x4 w1 = *(const f32x4*)&Ws[hl * 64 + wm + 16 + quad * 4];
      #pragma unroll
      for (int nt = 0; nt < 4; ++nt)
        #pragma unroll
        for (int r = 0; r < 4; ++r) {
          sacc[0][nt][r] += w0[r] * fmaxf(lg[0][nt][r], 0.f);
          sacc[1][nt][r] += w1[r] * fmaxf(lg[1][nt][r], 0.f);
        }
    }
  }

  const float scale = 0.088388347648318447f;  // 128^-0.5
  #pragma unroll
  for (int mt = 0; mt < 2; ++mt)
    #pragma unroll
    for (int nt = 0; nt < 4; ++nt)
      #pragma unroll
      for (int r = 0; r < 4; ++r) {
        int qq = q0 + wm + mt * 16 + quad * 4 + r;
        int kk = k0 + wn + nt * 16 + row;
        unsafeAtomicAdd(&out[((size_t)b << 20) + (size_t)qq * 1024 + kk], scale * sacc[mt][nt][r]);
      }
}

extern "C" void kernel_launch(void* const* d_in, const int* in_sizes, int n_in,
                              void* d_out, int out_size, void* d_ws, size_t ws_size,
                              hipStream_t stream) {
  const float* x    = (const float*)d_in[0];   // [2048][7168]
  const float* qr   = (const float*)d_in[1];   // [2048][1536]
  const float* cosb = (const float*)d_in[2];   // [2048][64]
  const float* sinb = (const float*)d_in[3];   // [2048][64]
  const float* wq   = (const float*)d_in[4];   // [1536][8192]
  const float* wk   = (const float*)d_in[5];   // [7168][128]
  const float* wp   = (const float*)d_in[6];   // [7168][64]
  const float* gam  = (const float*)d_in[7];   // [128]
  const float* bet  = (const float*)d_in[8];   // [128]
  float* out = (float*)d_out;                  // [2][1024][1024] f32

  char* ws = (char*)d_ws;
  float* P    = (float*)(ws + 0);          // [16][2048][192] f32 = 25,165,824 B (proj phase)
  u16*   wqT  = (u16*)(ws + 0);            // [8192][1536] bf16 (after reduce; same region)
  u16*   wkwpT= (u16*)(ws + 25165824);     // [192][7168] bf16 = 2,752,512 B
  float* WT   = (float*)(ws + 27918336);   // [64][2048] f32 = 524,288 B (transposed W)
  u16*   Kbf  = (u16*)(ws + 28442624);     // [2048][128] bf16 = 524,288 B
  u16*   Qbf  = (u16*)(ws + 28966912);     // [2048][8192] bf16 = 33,554,432 B -> 62,521,344
  const size_t QRB_OFF = 62521344;
  u16*   qrb  = (u16*)(ws + QRB_OFF);      // [2048][1536] bf16 = 6,291,456 B -> 68,812,800
  const bool big_ws = (ws_size >= (size_t)68812800);

  (void)in_sizes; (void)n_in;

  hipMemsetAsync(d_out, 0, (size_t)out_size * 4, stream);

  transpose_f32_bf16<<<dim3(4, 224),  256, 0, stream>>>(wk, wkwpT,              7168, 128);
  transpose_f32_bf16<<<dim3(2, 224),  256, 0, stream>>>(wp, wkwpT + 128 * 7168, 7168, 64);

  proj_splitk<<<dim3(16, 32), 256, 0, stream>>>(x, wkwpT, P);
  reduce_lnrope<<<2048, 64, 0, stream>>>(P, cosb, sinb, gam, bet, Kbf, WT);

  transpose_f32_bf16<<<dim3(256, 48), 256, 0, stream>>>(wq, wqT, 1536, 8192);

  if (big_ws) {
    cvt_f32_bf16<<<1536, 256, 0, stream>>>(qr, qrb);
    qgemm<true><<<dim3(64, 16), 256, 0, stream>>>(qrb, wqT, cosb, sinb, Qbf);
  } else {
    qgemm<false><<<dim3(64, 16), 256, 0, stream>>>(qr, wqT, cosb, sinb, Qbf);
  }

  attn_kernel<<<512, 256, 0, stream>>>(Qbf, Kbf, WT, out);
}

// Round 5
// 328.261 us; speedup vs baseline: 2.3758x; 1.0170x over previous
//
#include <hip/hip_runtime.h>

typedef unsigned short u16;
typedef unsigned int   u32;

typedef __bf16 bf16x8 __attribute__((ext_vector_type(8)));
typedef float  f32x4  __attribute__((ext_vector_type(4)));

__device__ __forceinline__ float bf2f(u16 u){ u32 x = ((u32)u) << 16; return __builtin_bit_cast(float, x); }
__device__ __forceinline__ u16 f2bf(float f){
  u32 u = __builtin_bit_cast(u32, f);
  u32 r = (u + 0x7FFFu + ((u >> 16) & 1u)) >> 16;
  return (u16)r;
}
// pack bf16(a) low16, bf16(b) high16
__device__ __forceinline__ u32 pk2bf(float a, float b){
  u32 ua = __builtin_bit_cast(u32, a) + 0x8000u;
  u32 ub = __builtin_bit_cast(u32, b) + 0x8000u;
  return __builtin_amdgcn_perm(ub, ua, 0x07060302u);
}
// async global->LDS, 16B/lane; lds base wave-uniform, dest = base + lane*16
__device__ __forceinline__ void glds16(const void* g, void* l){
  __builtin_amdgcn_global_load_lds((const __attribute__((address_space(1))) void*)g,
                                   (__attribute__((address_space(3))) void*)l, 16, 0, 0);
}

// ---------------- vectorized transpose + cast: f32 [R][C] -> bf16 [C][R], 64x64 tiles ----------------
__global__ __launch_bounds__(256) void transpose_f32_bf16_v(const float* __restrict__ src,
                                                            u16* __restrict__ dst, int R, int C){
  __shared__ u16 T[64 * 72];            // [c][r], stride 72 u16 = 144 B (16B-aligned rows)
  int c0 = blockIdx.x * 64, r0 = blockIdx.y * 64;
  int tr  = threadIdx.x >> 3;           // 0..31
  int tc8 = (threadIdx.x & 7) * 8;
  #pragma unroll
  for (int it = 0; it < 2; ++it){
    int rr = tr + it * 32;
    const float* sp = src + (size_t)(r0 + rr) * C + c0 + tc8;
    float4 f0 = *(const float4*)sp, f1 = *(const float4*)(sp + 4);
    u16 v[8] = { f2bf(f0.x), f2bf(f0.y), f2bf(f0.z), f2bf(f0.w),
                 f2bf(f1.x), f2bf(f1.y), f2bf(f1.z), f2bf(f1.w) };
    #pragma unroll
    for (int j = 0; j < 8; ++j) T[(tc8 + j) * 72 + rr] = v[j];
  }
  __syncthreads();
  int tcw = threadIdx.x >> 3;
  int tr8 = (threadIdx.x & 7) * 8;
  #pragma unroll
  for (int it = 0; it < 2; ++it){
    int cc = tcw + it * 32;
    *(uint4*)(dst + (size_t)(c0 + cc) * R + r0 + tr8) = *(const uint4*)&T[cc * 72 + tr8];
  }
}

// ---------------- f32 -> bf16 bulk convert (8 elems/thread) ----------------
__global__ __launch_bounds__(256) void cvt_f32_bf16(const float* __restrict__ src,
                                                    u16* __restrict__ dst){
  size_t i = ((size_t)blockIdx.x * 256 + threadIdx.x) * 8;
  const float4* a4 = (const float4*)(src + i);
  float4 f0 = a4[0], f1 = a4[1];
  u32 w[4] = { pk2bf(f0.x, f0.y), pk2bf(f0.z, f0.w), pk2bf(f1.x, f1.y), pk2bf(f1.z, f1.w) };
  *(uint4*)(dst + i) = *(const uint4*)w;
}

// ---------------- split-K projection: P[s][m][0..191] = x[m][ks] @ [wk;wp][ks] ----------------
__global__ __launch_bounds__(256) void proj_splitk(const float* __restrict__ X,
    const u16* __restrict__ BT, float* __restrict__ P){
  constexpr int Kf = 7168;
  const int s = blockIdx.x, m0 = blockIdx.y * 64;
  const int kbase = s * 448;
  __shared__ u16 As[2 * 64 * 36];      // [kc][64][36] padded (VALU-packed stores)
  __shared__ u16 Bs[2 * 192 * 32];     // [kc][192][32] unpadded (glds)
  const int tid = threadIdx.x, wave = tid >> 6, lane = tid & 63;
  const int row = lane & 15, quad = lane >> 4;
  const int wm = (wave & 1) * 32, wn = (wave >> 1) * 96;

  const f32x4 zero = {0.f, 0.f, 0.f, 0.f};
  f32x4 acc[2][6];
  #pragma unroll
  for (int mt = 0; mt < 2; ++mt)
    #pragma unroll
    for (int nt = 0; nt < 6; ++nt) acc[mt][nt] = zero;

  for (int kb = 0; kb < 7; ++kb) {
    int k0 = kbase + kb * 64;
    #pragma unroll
    for (int c = 0; c < 6; ++c) {
      int chunk = wave * 6 + c;
      int kc = chunk / 12, rem = chunk % 12;
      int r = rem * 16 + (lane >> 2), col = (lane & 3) * 8;
      glds16(BT + (size_t)r * Kf + k0 + kc * 32 + col, (void*)&Bs[chunk * 512]);
    }
    #pragma unroll
    for (int c = 0; c < 2; ++c) {
      int idx = tid + c * 256;
      int r = idx >> 3, kf = (idx & 7) * 8;
      const float4* ap = (const float4*)(X + (size_t)(m0 + r) * Kf + k0 + kf);
      float4 f0 = ap[0], f1 = ap[1];
      u32 w[4] = { pk2bf(f0.x, f0.y), pk2bf(f0.z, f0.w), pk2bf(f1.x, f1.y), pk2bf(f1.z, f1.w) };
      *(uint4*)&As[(kf >> 5) * 2304 + r * 36 + (kf & 31)] = *(const uint4*)w;
    }
    __syncthreads();
    #pragma unroll
    for (int ks = 0; ks < 2; ++ks) {
      bf16x8 af[2], bfr[6];
      #pragma unroll
      for (int mt = 0; mt < 2; ++mt) af[mt] = *(const bf16x8*)&As[ks * 2304 + (wm + mt * 16 + row) * 36 + quad * 8];
      #pragma unroll
      for (int nt = 0; nt < 6; ++nt) bfr[nt] = *(const bf16x8*)&Bs[ks * 6144 + (wn + nt * 16 + row) * 32 + quad * 8];
      #pragma unroll
      for (int mt = 0; mt < 2; ++mt)
        #pragma unroll
        for (int nt = 0; nt < 6; ++nt)
          acc[mt][nt] = __builtin_amdgcn_mfma_f32_16x16x32_bf16(af[mt], bfr[nt], acc[mt][nt], 0, 0, 0);
    }
    __syncthreads();
  }
  #pragma unroll
  for (int mt = 0; mt < 2; ++mt)
    #pragma unroll
    for (int nt = 0; nt < 6; ++nt)
      #pragma unroll
      for (int r = 0; r < 4; ++r) {
        int rr = m0 + wm + mt * 16 + quad * 4 + r;
        int cc = wn + nt * 16 + row;
        P[((size_t)s * 2048 + rr) * 192 + cc] = acc[mt][nt][r];
      }
}

// ---------------- reduce 16 partials + LayerNorm + RoPE -> Kbf (bf16), WT (f32, [h][tok]) ----------------
__global__ __launch_bounds__(64) void reduce_lnrope(const float* __restrict__ P,
    const float* __restrict__ cosb, const float* __restrict__ sinb,
    const float* __restrict__ gam, const float* __restrict__ bet,
    u16* __restrict__ Kout, float* __restrict__ WoutT){
  int tok = blockIdx.x, lane = threadIdx.x;
  float v0 = 0.f, v1 = 0.f, w = 0.f;
  #pragma unroll
  for (int s = 0; s < 16; ++s) {
    const float* p = P + ((size_t)s * 2048 + tok) * 192;
    v0 += p[2 * lane]; v1 += p[2 * lane + 1]; w += p[128 + lane];
  }
  WoutT[(size_t)lane * 2048 + tok] = w;     // transposed: [h][tok]
  float sm = v0 + v1;
  #pragma unroll
  for (int m = 1; m < 64; m <<= 1) sm += __shfl_xor(sm, m);
  float mu = sm * (1.f / 128.f);
  float d0 = v0 - mu, d1 = v1 - mu;
  float sq = d0 * d0 + d1 * d1;
  #pragma unroll
  for (int m = 1; m < 64; m <<= 1) sq += __shfl_xor(sq, m);
  float rs = rsqrtf(sq * (1.f / 128.f) + 1e-6f);
  float kn0 = d0 * rs * gam[2 * lane]     + bet[2 * lane];
  float kn1 = d1 * rs * gam[2 * lane + 1] + bet[2 * lane + 1];
  float o0 = kn0, o1 = kn1;
  if (lane < 32) {
    float c  = cosb[tok * 64 + 2 * lane];
    float sn = sinb[tok * 64 + 2 * lane];
    o0 = kn0 * c - kn1 * sn;
    o1 = kn1 * c + kn0 * sn;
  }
  Kout[tok * 128 + 2 * lane]     = f2bf(o0);
  Kout[tok * 128 + 2 * lane + 1] = f2bf(o1);
}

// ---------------- Q-GEMM (M=2048,N=8192,K=1536), BK=64, fused RoPE epilogue (unchanged control) ----------------
template<bool AGLDS>
__global__ __launch_bounds__(256) void qgemm(const void* __restrict__ Aptr,
    const u16* __restrict__ BT, const float* __restrict__ cosb,
    const float* __restrict__ sinb, u16* __restrict__ Qout){
  constexpr int K = 1536, N = 8192;
  __shared__ u16 As[2 * 128 * 32];   // [kc][128][32] unpadded (glds / packed stores)
  __shared__ u16 Bs[2 * 128 * 32];
  const int tid = threadIdx.x, wave = tid >> 6, lane = tid & 63;
  const int row = lane & 15, quad = lane >> 4;
  const int wm = (wave >> 1) * 64, wn = (wave & 1) * 64;
  const int m0 = blockIdx.y * 128, n0 = blockIdx.x * 128;

  const f32x4 zero = {0.f, 0.f, 0.f, 0.f};
  f32x4 acc[4][4];
  #pragma unroll
  for (int mt = 0; mt < 4; ++mt)
    #pragma unroll
    for (int nt = 0; nt < 4; ++nt) acc[mt][nt] = zero;

  for (int k0 = 0; k0 < K; k0 += 64) {
    #pragma unroll
    for (int c = 0; c < 4; ++c) {            // B: 16 chunks (1024B), 4/wave
      int chunk = wave * 4 + c;
      int kc = chunk >> 3, rg = chunk & 7;
      int r = rg * 16 + (lane >> 2), col = kc * 32 + (lane & 3) * 8;
      glds16(BT + (size_t)(n0 + r) * K + k0 + col, (void*)&Bs[chunk * 512]);
    }
    if (AGLDS) {
      #pragma unroll
      for (int c = 0; c < 4; ++c) {
        int chunk = wave * 4 + c;
        int kc = chunk >> 3, rg = chunk & 7;
        int r = rg * 16 + (lane >> 2), col = kc * 32 + (lane & 3) * 8;
        glds16((const u16*)Aptr + (size_t)(m0 + r) * K + k0 + col, (void*)&As[chunk * 512]);
      }
    } else {
      #pragma unroll
      for (int c = 0; c < 4; ++c) {          // A: f32 load + pack, 128x64
        int idx = tid + c * 256;
        int r = idx >> 3, kf = (idx & 7) * 8;
        const float4* ap = (const float4*)((const float*)Aptr + (size_t)(m0 + r) * K + k0 + kf);
        float4 f0 = ap[0], f1 = ap[1];
        u32 w[4] = { pk2bf(f0.x, f0.y), pk2bf(f0.z, f0.w), pk2bf(f1.x, f1.y), pk2bf(f1.z, f1.w) };
        *(uint4*)&As[(kf >> 5) * 4096 + r * 32 + (kf & 31)] = *(const uint4*)w;
      }
    }
    __syncthreads();
    #pragma unroll
    for (int kk = 0; kk < 2; ++kk) {
      bf16x8 af[4], bfr[4];
      #pragma unroll
      for (int mt = 0; mt < 4; ++mt) af[mt]  = *(const bf16x8*)&As[kk * 4096 + (wm + mt * 16 + row) * 32 + quad * 8];
      #pragma unroll
      for (int nt = 0; nt < 4; ++nt) bfr[nt] = *(const bf16x8*)&Bs[kk * 4096 + (wn + nt * 16 + row) * 32 + quad * 8];
      #pragma unroll
      for (int mt = 0; mt < 4; ++mt)
        #pragma unroll
        for (int nt = 0; nt < 4; ++nt)
          acc[mt][nt] = __builtin_amdgcn_mfma_f32_16x16x32_bf16(af[mt], bfr[nt], acc[mt][nt], 0, 0, 0);
    }
    __syncthreads();
  }

  const bool roped = (wn == 0);
  #pragma unroll
  for (int mt = 0; mt < 4; ++mt)
    #pragma unroll
    for (int nt = 0; nt < 4; ++nt)
      #pragma unroll
      for (int r = 0; r < 4; ++r) {
        int rr = m0 + wm + mt * 16 + quad * 4 + r;
        int cc = n0 + wn + nt * 16 + row;
        float v = acc[mt][nt][r];
        float o = v;
        if (roped) {
          int hd = (wn + nt * 16 + row) & 127;
          float c = cosb[rr * 64 + hd];
          float s = sinb[rr * 64 + hd];
          float vo = __shfl_xor(v, 1);
          o = (cc & 1) ? (v * c + vo * s) : (v * c - vo * s);
        }
        Qout[(size_t)rr * N + cc] = f2bf(o);
      }
}

// ---------------- fused scores: double-buffered Q stage, ONE barrier per 2-head pair ----------------
__global__ __launch_bounds__(256) void attn_kernel(const u16* __restrict__ Q,
    const u16* __restrict__ Kb, const float* __restrict__ WT, float* __restrict__ out){
  int blk = blockIdx.x;                       // 512 blocks
  int x = blk & 7, kt = (blk >> 3) & 7, hs = (blk >> 6) & 1, g4 = (blk >> 7) & 3;
  int p = x + 8 * g4;                         // 0..31
  int b = p >> 4, qt = p & 15;
  int q0 = qt * 64, k0 = kt * 128;

  const int tid = threadIdx.x, wave = tid >> 6, lane = tid & 63;
  const int row = lane & 15, quad = lane >> 4;
  const int wm = (wave >> 1) * 32;            // q offset (0/32)
  const int wn = (wave & 1) * 64;             // k offset (0/64)

  __shared__ u16 Sh[2][16384];                // 2 x 32 KB buffers; Sh[0] first holds the K tile
  __shared__ float Ws[32 * 64];               // 8 KB: [h_local][q_local]

  // stage K tile 128x128 into Sh[0] as [r][128]
  #pragma unroll
  for (int c = 0; c < 8; ++c) {
    int g = wave * 8 + c;
    int rr = g * 4 + (lane >> 4), col = (lane & 15) * 8;
    glds16(Kb + (size_t)(b * 1024 + k0 + rr) * 128 + col, (void*)&Sh[0][g * 512]);
  }
  {
    int hl = tid >> 3, qq = (tid & 7) * 8;
    const float* srcw = WT + (size_t)(hs * 32 + hl) * 2048 + b * 1024 + q0 + qq;
    *(float4*)&Ws[hl * 64 + qq]     = *(const float4*)srcw;
    *(float4*)&Ws[hl * 64 + qq + 4] = *(const float4*)(srcw + 4);
  }
  __syncthreads();

  bf16x8 bfr[4][4];                           // h-invariant K fragments (read once)
  #pragma unroll
  for (int ks = 0; ks < 4; ++ks)
    #pragma unroll
    for (int nt = 0; nt < 4; ++nt)
      bfr[ks][nt] = *(const bf16x8*)&Sh[0][(wn + nt * 16 + row) * 128 + ks * 32 + quad * 8];
  __syncthreads();                            // all waves done reading K before Q overwrites Sh[0]

  const u16* Qbase = Q + (size_t)(b * 1024 + q0) * 8192;
  auto stage = [&](int half, int pairIdx){    // stage 2 heads (32 KB): 32 chunks, 8/wave
    int h0 = hs * 32 + pairIdx * 2;
    #pragma unroll
    for (int c = 0; c < 8; ++c) {
      int g = wave * 8 + c;
      int hsub = g >> 4, rem = g & 15;
      int kc = rem >> 2, rg = rem & 3;
      glds16(Qbase + (size_t)(rg * 16 + (lane >> 2)) * 8192 + (h0 + hsub) * 128 + kc * 32 + (lane & 3) * 8,
             (void*)&Sh[half][hsub * 8192 + rem * 512]);
    }
  };

  const f32x4 zero = {0.f, 0.f, 0.f, 0.f};
  f32x4 sacc[2][4];
  #pragma unroll
  for (int mt = 0; mt < 2; ++mt)
    #pragma unroll
    for (int nt = 0; nt < 4; ++nt) sacc[mt][nt] = zero;

  stage(0, 0);                                // prefetch pair 0
  for (int hp = 0; hp < 16; ++hp) {
    __syncthreads();                          // drains pair hp's glds (in shadow for hp>=1)
    if (hp < 15) stage((hp + 1) & 1, hp + 1); // prefetch next pair before compute
    const u16* S = Sh[hp & 1];
    #pragma unroll
    for (int hsub = 0; hsub < 2; ++hsub) {
      f32x4 lg[2][4];
      #pragma unroll
      for (int mt = 0; mt < 2; ++mt)
        #pragma unroll
        for (int nt = 0; nt < 4; ++nt) lg[mt][nt] = zero;
      #pragma unroll
      for (int ks = 0; ks < 4; ++ks) {
        bf16x8 af0 = *(const bf16x8*)&S[hsub * 8192 + ks * 2048 + (wm +      row) * 32 + quad * 8];
        bf16x8 af1 = *(const bf16x8*)&S[hsub * 8192 + ks * 2048 + (wm + 16 + row) * 32 + quad * 8];
        #pragma unroll
        for (int nt = 0; nt < 4; ++nt) {
          lg[0][nt] = __builtin_amdgcn_mfma_f32_16x16x32_bf16(af0, bfr[ks][nt], lg[0][nt], 0, 0, 0);
          lg[1][nt] = __builtin_amdgcn_mfma_f32_16x16x32_bf16(af1, bfr[ks][nt], lg[1][nt], 0, 0, 0);
        }
      }
      int hl = hp * 2 + hsub;
      f32x4 w0 = *(const f32x4*)&Ws[hl * 64 + wm +      quad * 4];
      f32x4 w1 = *(const f32x4*)&Ws[hl * 64 + wm + 16 + quad * 4];
      #pragma unroll
      for (int nt = 0; nt < 4; ++nt)
        #pragma unroll
        for (int r = 0; r < 4; ++r) {
          sacc[0][nt][r] += w0[r] * fmaxf(lg[0][nt][r], 0.f);
          sacc[1][nt][r] += w1[r] * fmaxf(lg[1][nt][r], 0.f);
        }
    }
  }

  const float scale = 0.088388347648318447f;  // 128^-0.5
  #pragma unroll
  for (int mt = 0; mt < 2; ++mt)
    #pragma unroll
    for (int nt = 0; nt < 4; ++nt)
      #pragma unroll
      for (int r = 0; r < 4; ++r) {
        int qq = q0 + wm + mt * 16 + quad * 4 + r;
        int kk = k0 + wn + nt * 16 + row;
        unsafeAtomicAdd(&out[((size_t)b << 20) + (size_t)qq * 1024 + kk], scale * sacc[mt][nt][r]);
      }
}

extern "C" void kernel_launch(void* const* d_in, const int* in_sizes, int n_in,
                              void* d_out, int out_size, void* d_ws, size_t ws_size,
                              hipStream_t stream) {
  const float* x    = (const float*)d_in[0];   // [2048][7168]
  const float* qr   = (const float*)d_in[1];   // [2048][1536]
  const float* cosb = (const float*)d_in[2];   // [2048][64]
  const float* sinb = (const float*)d_in[3];   // [2048][64]
  const float* wq   = (const float*)d_in[4];   // [1536][8192]
  const float* wk   = (const float*)d_in[5];   // [7168][128]
  const float* wp   = (const float*)d_in[6];   // [7168][64]
  const float* gam  = (const float*)d_in[7];   // [128]
  const float* bet  = (const float*)d_in[8];   // [128]
  float* out = (float*)d_out;                  // [2][1024][1024] f32

  char* ws = (char*)d_ws;
  float* P    = (float*)(ws + 0);          // [16][2048][192] f32 = 25,165,824 B (proj phase)
  u16*   wqT  = (u16*)(ws + 0);            // [8192][1536] bf16 (after reduce; same region)
  u16*   wkwpT= (u16*)(ws + 25165824);     // [192][7168] bf16 = 2,752,512 B
  float* WT   = (float*)(ws + 27918336);   // [64][2048] f32 = 524,288 B (transposed W)
  u16*   Kbf  = (u16*)(ws + 28442624);     // [2048][128] bf16 = 524,288 B
  u16*   Qbf  = (u16*)(ws + 28966912);     // [2048][8192] bf16 = 33,554,432 B -> 62,521,344
  const size_t QRB_OFF = 62521344;
  u16*   qrb  = (u16*)(ws + QRB_OFF);      // [2048][1536] bf16 = 6,291,456 B -> 68,812,800
  const bool big_ws = (ws_size >= (size_t)68812800);

  (void)in_sizes; (void)n_in;

  hipMemsetAsync(d_out, 0, (size_t)out_size * 4, stream);

  transpose_f32_bf16_v<<<dim3(2, 112), 256, 0, stream>>>(wk, wkwpT,              7168, 128);
  transpose_f32_bf16_v<<<dim3(1, 112), 256, 0, stream>>>(wp, wkwpT + 128 * 7168, 7168, 64);

  proj_splitk<<<dim3(16, 32), 256, 0, stream>>>(x, wkwpT, P);
  reduce_lnrope<<<2048, 64, 0, stream>>>(P, cosb, sinb, gam, bet, Kbf, WT);

  transpose_f32_bf16_v<<<dim3(128, 24), 256, 0, stream>>>(wq, wqT, 1536, 8192);

  if (big_ws) {
    cvt_f32_bf16<<<1536, 256, 0, stream>>>(qr, qrb);
    qgemm<true><<<dim3(64, 16), 256, 0, stream>>>(qrb, wqT, cosb, sinb, Qbf);
  } else {
    qgemm<false><<<dim3(64, 16), 256, 0, stream>>>(qr, wqT, cosb, sinb, Qbf);
  }

  attn_kernel<<<512, 256, 0, stream>>>(Qbf, Kbf, WT, out);
}